// Round 1
// baseline (1509.832 us; speedup 1.0000x reference)
//
#include <hip/hip_runtime.h>
#include <math.h>

#define HW     16384
#define IMG_H  128
#define IMG_W  128

// ws layout in floats
#define OFF_TOFF  ((size_t)0)
#define OFF_TM    ((size_t)8388608)
#define OFF_XT    ((size_t)16777216)
#define OFF_WT    ((size_t)25165824)
#define OFF_WDEF  ((size_t)25172736)
#define OFF_STAT  ((size_t)25181952)
#define OFF_AD    ((size_t)25181984)

// ---------------------------------------------------------------------------
// k_prep: build wT[c][108] (pw weights, c-major) and wdefT[g][k][c][o];
// zero the 32 stats floats.
__global__ void k_prep(const float* __restrict__ wpw_off,
                       const float* __restrict__ wpw_m,
                       const float* __restrict__ wdef,
                       float* __restrict__ ws) {
    int i = blockIdx.x * 256 + threadIdx.x;
    if (i < 32) ws[OFF_STAT + i] = 0.f;
    if (i < 6912) {
        int c = i / 108, o = i % 108;
        ws[OFF_WT + i] = (o < 72) ? wpw_off[o * 64 + c] : wpw_m[(o - 72) * 64 + c];
    } else if (i < 16128) {
        int j = i - 6912;               // j = ((g*9+k)*16+c)*16+o
        int o = j & 15;
        int c = (j >> 4) & 15;
        int t = j >> 8;                 // g*9+k
        int k = t % 9, g = t / 9;
        ws[OFF_WDEF + j] = wdef[((g * 16 + o) * 16 + c) * 9 + k];
    }
}

// ---------------------------------------------------------------------------
// k_trans: x[B,C,H,W] -> xT[b][g][p][16]  (channels-last within deform group)
__global__ __launch_bounds__(256) void k_trans(const float* __restrict__ x,
                                               float* __restrict__ xT) {
    int n = blockIdx.x * 256 + threadIdx.x;     // n = (b*4+g)*HW + p
    int p = n & (HW - 1);
    int bg = n >> 14;
    const float* src = x + (size_t)bg * 16 * HW + p;
    float v[16];
#pragma unroll
    for (int c = 0; c < 16; ++c) v[c] = src[(size_t)c * HW];
    float4* dst = (float4*)(xT + (size_t)n * 16);
    dst[0] = make_float4(v[0], v[1], v[2], v[3]);
    dst[1] = make_float4(v[4], v[5], v[6], v[7]);
    dst[2] = make_float4(v[8], v[9], v[10], v[11]);
    dst[3] = make_float4(v[12], v[13], v[14], v[15]);
}

// ---------------------------------------------------------------------------
// k_dw: both depthwise 7x7 convs fused + per-sample sum/sumsq stats.
// block = (b,c, 8-row stripe); thread: 1 col x 4 rows.
__global__ __launch_bounds__(256) void k_dw(const float* __restrict__ x,
                                            const float* __restrict__ wdwo,
                                            const float* __restrict__ bdwo,
                                            const float* __restrict__ wdwm,
                                            const float* __restrict__ bdwm,
                                            float* __restrict__ t_off,
                                            float* __restrict__ t_m,
                                            float* __restrict__ stats) {
    int bid = blockIdx.x;
    int plane = bid >> 4;                   // b*64+c
    int stripe = (bid & 15) * 8;
    int t = threadIdx.x;
    int col = t & 127;
    int r0 = stripe + (t >> 7) * 4;
    int c = plane & 63, b = plane >> 6;
    const float* pl = x + (size_t)plane * HW;
    const float* wo = wdwo + c * 49;
    const float* wm = wdwm + c * 49;

    float ao[4] = {0.f, 0.f, 0.f, 0.f};
    float am[4] = {0.f, 0.f, 0.f, 0.f};
#pragma unroll
    for (int j = 0; j < 10; ++j) {
        int iy = r0 - 3 + j;
        int iyc = iy < 0 ? 0 : (iy > 127 ? 127 : iy);
        bool rok = (iy >= 0) && (iy < IMG_H);
#pragma unroll
        for (int dx = 0; dx < 7; ++dx) {
            int ix = col - 3 + dx;
            int ixc = ix < 0 ? 0 : (ix > 127 ? 127 : ix);
            float raw = pl[iyc * IMG_W + ixc];
            float v = (rok && ix >= 0 && ix < IMG_W) ? raw : 0.f;
#pragma unroll
            for (int rr = 0; rr < 4; ++rr) {
                int dy = j - rr;                 // compile-time after unroll
                if (dy >= 0 && dy < 7) {
                    ao[rr] = fmaf(wo[dy * 7 + dx], v, ao[rr]);
                    am[rr] = fmaf(wm[dy * 7 + dx], v, am[rr]);
                }
            }
        }
    }
    float bo = bdwo[c], bm = bdwm[c];
    float s1o = 0.f, s2o = 0.f, s1m = 0.f, s2m = 0.f;
#pragma unroll
    for (int rr = 0; rr < 4; ++rr) {
        float vo = ao[rr] + bo, vm = am[rr] + bm;
        size_t idx = (size_t)plane * HW + (size_t)(r0 + rr) * IMG_W + col;
        t_off[idx] = vo;
        t_m[idx] = vm;
        s1o += vo; s2o += vo * vo; s1m += vm; s2m += vm * vm;
    }
#pragma unroll
    for (int d = 32; d; d >>= 1) {
        s1o += __shfl_down(s1o, d);
        s2o += __shfl_down(s2o, d);
        s1m += __shfl_down(s1m, d);
        s2m += __shfl_down(s2m, d);
    }
    if ((t & 63) == 0) {
        atomicAdd(&stats[b * 4 + 0], s1o);
        atomicAdd(&stats[b * 4 + 1], s2o);
        atomicAdd(&stats[b * 4 + 2], s1m);
        atomicAdd(&stats[b * 4 + 3], s2m);
    }
}

// ---------------------------------------------------------------------------
// k_fin: fold GroupNorm into per-(b,c) affine:  n = a*t + d
__global__ void k_fin(const float* __restrict__ stats,
                      const float* __restrict__ gog, const float* __restrict__ gob,
                      const float* __restrict__ gmg, const float* __restrict__ gmb,
                      float* __restrict__ ad) {
    int i = blockIdx.x * 256 + threadIdx.x;     // b*64+c
    if (i >= 512) return;
    int b = i >> 6, c = i & 63;
    const float invN = 1.f / 1048576.f;
    float m_o = stats[b * 4 + 0] * invN;
    float v_o = stats[b * 4 + 1] * invN - m_o * m_o;
    float i_o = rsqrtf(v_o + 1e-5f);
    float m_m = stats[b * 4 + 2] * invN;
    float v_m = stats[b * 4 + 3] * invN - m_m * m_m;
    float i_m = rsqrtf(v_m + 1e-5f);
    float a_o = i_o * gog[c];
    float d_o = gob[c] - m_o * a_o;
    float a_m = i_m * gmg[c];
    float d_m = gmb[c] - m_m * a_m;
    float4* dst = (float4*)(ad + (size_t)i * 4);
    *dst = make_float4(a_o, d_o, a_m, d_m);
}

// ---------------------------------------------------------------------------
// k_mega: per output pixel: pw GEMM (108 outs) + softmax + bilinear deform conv.
__global__ __launch_bounds__(256) void k_mega(const float* __restrict__ t_off,
                                              const float* __restrict__ t_m,
                                              const float* __restrict__ xT,
                                              const float* __restrict__ wT,
                                              const float* __restrict__ wdefT,
                                              const float* __restrict__ ad,
                                              const float* __restrict__ bpo,
                                              const float* __restrict__ bpm,
                                              const float* __restrict__ bias,
                                              float* __restrict__ out) {
    int tid = threadIdx.x;
    int bid = blockIdx.x;
    int b = bid >> 6;
    int p = (bid & 63) * 256 + tid;
    int row = p >> 7, col = p & 127;

    float facc[72], macc[36];
#pragma unroll
    for (int o = 0; o < 72; ++o) facc[o] = bpo[o];
#pragma unroll
    for (int o = 0; o < 36; ++o) macc[o] = bpm[o];

    const float* adb = ad + b * 256;
    const float* to = t_off + (size_t)b * 64 * HW + p;
    const float* tm = t_m + (size_t)b * 64 * HW + p;
#pragma unroll 4
    for (int c = 0; c < 64; ++c) {
        float aof = adb[c * 4 + 0], dof = adb[c * 4 + 1];
        float amf = adb[c * 4 + 2], dmf = adb[c * 4 + 3];
        float no = fmaf(aof, to[c * HW], dof);
        float nm = fmaf(amf, tm[c * HW], dmf);
        const float* wr = wT + c * 108;
#pragma unroll
        for (int o = 0; o < 72; ++o) facc[o] = fmaf(wr[o], no, facc[o]);
#pragma unroll
        for (int o = 0; o < 36; ++o) macc[o] = fmaf(wr[72 + o], nm, macc[o]);
    }

    // softmax over k within each group
#pragma unroll
    for (int g = 0; g < 4; ++g) {
        float mx = macc[g * 9];
#pragma unroll
        for (int k = 1; k < 9; ++k) mx = fmaxf(mx, macc[g * 9 + k]);
        float s = 0.f;
#pragma unroll
        for (int k = 0; k < 9; ++k) {
            float e = __expf(macc[g * 9 + k] - mx);
            macc[g * 9 + k] = e;
            s += e;
        }
        float inv = 1.f / s;
#pragma unroll
        for (int k = 0; k < 9; ++k) macc[g * 9 + k] *= inv;
    }

    float* outp = out + (size_t)b * 64 * HW + p;
#pragma unroll
    for (int g = 0; g < 4; ++g) {
        float acc[16];
#pragma unroll
        for (int o = 0; o < 16; ++o) acc[o] = 0.f;
        const float* xg = xT + ((size_t)(b * 4 + g)) * HW * 16;
        const float* wg = wdefT + g * 2304;
#pragma unroll
        for (int k = 0; k < 9; ++k) {
            float py = (float)(row + k / 3 - 1) + facc[g * 18 + k * 2 + 0];
            float px = (float)(col + k % 3 - 1) + facc[g * 18 + k * 2 + 1];
            float y0f = floorf(py), x0f = floorf(px);
            float wy = py - y0f, wx = px - x0f;
            int iy0 = (int)y0f, ix0 = (int)x0f;
            int iy1 = iy0 + 1, ix1 = ix0 + 1;
            float fy0 = (iy0 >= 0 && iy0 < IMG_H) ? (1.f - wy) : 0.f;
            float fy1 = (iy1 >= 0 && iy1 < IMG_H) ? wy : 0.f;
            float fx0 = (ix0 >= 0 && ix0 < IMG_W) ? (1.f - wx) : 0.f;
            float fx1 = (ix1 >= 0 && ix1 < IMG_W) ? wx : 0.f;
            float mk = macc[g * 9 + k];
            float f00 = fy0 * fx0 * mk, f01 = fy0 * fx1 * mk;
            float f10 = fy1 * fx0 * mk, f11 = fy1 * fx1 * mk;
            int yc0 = iy0 < 0 ? 0 : (iy0 > 127 ? 127 : iy0);
            int yc1 = iy1 < 0 ? 0 : (iy1 > 127 ? 127 : iy1);
            int xc0 = ix0 < 0 ? 0 : (ix0 > 127 ? 127 : ix0);
            int xc1 = ix1 < 0 ? 0 : (ix1 > 127 ? 127 : ix1);
            const float* r00 = xg + (size_t)(yc0 * IMG_W + xc0) * 16;
            const float* r01 = xg + (size_t)(yc0 * IMG_W + xc1) * 16;
            const float* r10 = xg + (size_t)(yc1 * IMG_W + xc0) * 16;
            const float* r11 = xg + (size_t)(yc1 * IMG_W + xc1) * 16;
            const float* wk = wg + k * 256;
#pragma unroll 4
            for (int c = 0; c < 16; ++c) {
                float v = f00 * r00[c] + f01 * r01[c] + f10 * r10[c] + f11 * r11[c];
#pragma unroll
                for (int o = 0; o < 16; ++o)
                    acc[o] = fmaf(wk[c * 16 + o], v, acc[o]);
            }
        }
#pragma unroll
        for (int o = 0; o < 16; ++o)
            outp[(size_t)(g * 16 + o) * HW] = acc[o] + bias[g * 16 + o];
    }
}

// ---------------------------------------------------------------------------
extern "C" void kernel_launch(void* const* d_in, const int* in_sizes, int n_in,
                              void* d_out, int out_size, void* d_ws, size_t ws_size,
                              hipStream_t stream) {
    const float* x        = (const float*)d_in[0];
    const float* w_dw_off = (const float*)d_in[1];
    const float* b_dw_off = (const float*)d_in[2];
    const float* gn_off_g = (const float*)d_in[3];
    const float* gn_off_b = (const float*)d_in[4];
    const float* w_pw_off = (const float*)d_in[5];
    const float* b_pw_off = (const float*)d_in[6];
    const float* w_dw_m   = (const float*)d_in[7];
    const float* b_dw_m   = (const float*)d_in[8];
    const float* gn_m_g   = (const float*)d_in[9];
    const float* gn_m_b   = (const float*)d_in[10];
    const float* w_pw_m   = (const float*)d_in[11];
    const float* b_pw_m   = (const float*)d_in[12];
    const float* weight   = (const float*)d_in[13];
    const float* bias     = (const float*)d_in[14];

    float* ws = (float*)d_ws;
    float* t_off = ws + OFF_TOFF;
    float* t_m   = ws + OFF_TM;
    float* xT    = ws + OFF_XT;
    float* wT    = ws + OFF_WT;
    float* wdefT = ws + OFF_WDEF;
    float* stats = ws + OFF_STAT;
    float* adb   = ws + OFF_AD;

    k_prep<<<63, 256, 0, stream>>>(w_pw_off, w_pw_m, weight, ws);
    k_trans<<<2048, 256, 0, stream>>>(x, xT);
    k_dw<<<8192, 256, 0, stream>>>(x, w_dw_off, b_dw_off, w_dw_m, b_dw_m,
                                   t_off, t_m, stats);
    k_fin<<<2, 256, 0, stream>>>(stats, gn_off_g, gn_off_b, gn_m_g, gn_m_b, adb);
    k_mega<<<512, 256, 0, stream>>>(t_off, t_m, xT, wT, wdefT, adb,
                                    b_pw_off, b_pw_m, bias, (float*)d_out);
}

// Round 2
// 200.120 us; speedup vs baseline: 7.5446x; 7.5446x over previous
//
#include <hip/hip_runtime.h>
#include <math.h>

#define HW     16384
#define IMG_H  128
#define IMG_W  128

// ws layout in floats
#define OFF_TOFF  ((size_t)0)
#define OFF_TM    ((size_t)8388608)
#define OFF_XT    ((size_t)16777216)
#define OFF_WT    ((size_t)25165824)
#define OFF_WDEF  ((size_t)25172736)
#define OFF_PART  ((size_t)25181952)   // 8192 blocks x float4 partial stats
#define OFF_AD    ((size_t)25214720)   // 512 x float4 folded GN affine

// ---------------------------------------------------------------------------
// k_prep: build wT[c][108] (pw weights, c-major) and wdefT[g][k][c][o].
__global__ void k_prep(const float* __restrict__ wpw_off,
                       const float* __restrict__ wpw_m,
                       const float* __restrict__ wdef,
                       float* __restrict__ ws) {
    int i = blockIdx.x * 256 + threadIdx.x;
    if (i < 6912) {
        int c = i / 108, o = i % 108;
        ws[OFF_WT + i] = (o < 72) ? wpw_off[o * 64 + c] : wpw_m[(o - 72) * 64 + c];
    } else if (i < 16128) {
        int j = i - 6912;               // j = ((g*9+k)*16+c)*16+o
        int o = j & 15;
        int c = (j >> 4) & 15;
        int t = j >> 8;                 // g*9+k
        int k = t % 9, g = t / 9;
        ws[OFF_WDEF + j] = wdef[((g * 16 + o) * 16 + c) * 9 + k];
    }
}

// ---------------------------------------------------------------------------
// k_trans: x[B,C,H,W] -> xT[b][g][p][16]  (channels-last within deform group)
__global__ __launch_bounds__(256) void k_trans(const float* __restrict__ x,
                                               float* __restrict__ xT) {
    int n = blockIdx.x * 256 + threadIdx.x;     // n = (b*4+g)*HW + p
    int p = n & (HW - 1);
    int bg = n >> 14;
    const float* src = x + (size_t)bg * 16 * HW + p;
    float v[16];
#pragma unroll
    for (int c = 0; c < 16; ++c) v[c] = src[(size_t)c * HW];
    float4* dst = (float4*)(xT + (size_t)n * 16);
    dst[0] = make_float4(v[0], v[1], v[2], v[3]);
    dst[1] = make_float4(v[4], v[5], v[6], v[7]);
    dst[2] = make_float4(v[8], v[9], v[10], v[11]);
    dst[3] = make_float4(v[12], v[13], v[14], v[15]);
}

// ---------------------------------------------------------------------------
// k_dw: both depthwise 7x7 convs fused; per-block partial GN stats (no atomics).
// block = (b,c, 8-row stripe); thread: 1 col x 4 rows.
__global__ __launch_bounds__(256) void k_dw(const float* __restrict__ x,
                                            const float* __restrict__ wdwo,
                                            const float* __restrict__ bdwo,
                                            const float* __restrict__ wdwm,
                                            const float* __restrict__ bdwm,
                                            float* __restrict__ t_off,
                                            float* __restrict__ t_m,
                                            float* __restrict__ partial) {
    int bid = blockIdx.x;
    int plane = bid >> 4;                   // b*64+c
    int stripe = (bid & 15) * 8;
    int t = threadIdx.x;
    int col = t & 127;
    int r0 = stripe + (t >> 7) * 4;
    int c = plane & 63;
    const float* pl = x + (size_t)plane * HW;
    const float* wo = wdwo + c * 49;
    const float* wm = wdwm + c * 49;

    float ao[4] = {0.f, 0.f, 0.f, 0.f};
    float am[4] = {0.f, 0.f, 0.f, 0.f};
#pragma unroll
    for (int j = 0; j < 10; ++j) {
        int iy = r0 - 3 + j;
        int iyc = iy < 0 ? 0 : (iy > 127 ? 127 : iy);
        bool rok = (iy >= 0) && (iy < IMG_H);
#pragma unroll
        for (int dx = 0; dx < 7; ++dx) {
            int ix = col - 3 + dx;
            int ixc = ix < 0 ? 0 : (ix > 127 ? 127 : ix);
            float raw = pl[iyc * IMG_W + ixc];
            float v = (rok && ix >= 0 && ix < IMG_W) ? raw : 0.f;
#pragma unroll
            for (int rr = 0; rr < 4; ++rr) {
                int dy = j - rr;                 // compile-time after unroll
                if (dy >= 0 && dy < 7) {
                    ao[rr] = fmaf(wo[dy * 7 + dx], v, ao[rr]);
                    am[rr] = fmaf(wm[dy * 7 + dx], v, am[rr]);
                }
            }
        }
    }
    float bo = bdwo[c], bm = bdwm[c];
    float s1o = 0.f, s2o = 0.f, s1m = 0.f, s2m = 0.f;
#pragma unroll
    for (int rr = 0; rr < 4; ++rr) {
        float vo = ao[rr] + bo, vm = am[rr] + bm;
        size_t idx = (size_t)plane * HW + (size_t)(r0 + rr) * IMG_W + col;
        t_off[idx] = vo;
        t_m[idx] = vm;
        s1o += vo; s2o += vo * vo; s1m += vm; s2m += vm * vm;
    }
#pragma unroll
    for (int d = 32; d; d >>= 1) {
        s1o += __shfl_down(s1o, d);
        s2o += __shfl_down(s2o, d);
        s1m += __shfl_down(s1m, d);
        s2m += __shfl_down(s2m, d);
    }
    __shared__ float red[4][4];
    if ((t & 63) == 0) {
        int w = t >> 6;
        red[w][0] = s1o; red[w][1] = s2o; red[w][2] = s1m; red[w][3] = s2m;
    }
    __syncthreads();
    if (t < 4) {
        float v = red[0][t] + red[1][t] + red[2][t] + red[3][t];
        partial[(size_t)bid * 4 + t] = v;
    }
}

// ---------------------------------------------------------------------------
// k_fin: one block per sample. Reduce 1024 float4 partials -> GN stats, then
// fold GroupNorm into per-(b,c) affine:  n = a*t + d
__global__ __launch_bounds__(256) void k_fin(const float* __restrict__ partial,
                      const float* __restrict__ gog, const float* __restrict__ gob,
                      const float* __restrict__ gmg, const float* __restrict__ gmb,
                      float* __restrict__ ad) {
    int b = blockIdx.x, t = threadIdx.x;
    const float4* pp = (const float4*)partial + (size_t)b * 1024;
    float4 s = make_float4(0.f, 0.f, 0.f, 0.f);
#pragma unroll
    for (int i = 0; i < 4; ++i) {
        float4 v = pp[t + i * 256];
        s.x += v.x; s.y += v.y; s.z += v.z; s.w += v.w;
    }
#pragma unroll
    for (int d = 32; d; d >>= 1) {
        s.x += __shfl_down(s.x, d);
        s.y += __shfl_down(s.y, d);
        s.z += __shfl_down(s.z, d);
        s.w += __shfl_down(s.w, d);
    }
    __shared__ float red[4][4];
    if ((t & 63) == 0) {
        int w = t >> 6;
        red[w][0] = s.x; red[w][1] = s.y; red[w][2] = s.z; red[w][3] = s.w;
    }
    __syncthreads();
    if (t < 64) {
        float s1o = red[0][0] + red[1][0] + red[2][0] + red[3][0];
        float s2o = red[0][1] + red[1][1] + red[2][1] + red[3][1];
        float s1m = red[0][2] + red[1][2] + red[2][2] + red[3][2];
        float s2m = red[0][3] + red[1][3] + red[2][3] + red[3][3];
        int c = t;
        const float invN = 1.f / 1048576.f;
        float m_o = s1o * invN;
        float v_o = s2o * invN - m_o * m_o;
        float i_o = rsqrtf(v_o + 1e-5f);
        float m_m = s1m * invN;
        float v_m = s2m * invN - m_m * m_m;
        float i_m = rsqrtf(v_m + 1e-5f);
        float a_o = i_o * gog[c];
        float d_o = gob[c] - m_o * a_o;
        float a_m = i_m * gmg[c];
        float d_m = gmb[c] - m_m * a_m;
        ((float4*)ad)[b * 64 + c] = make_float4(a_o, d_o, a_m, d_m);
    }
}

// ---------------------------------------------------------------------------
// k_mega: per output pixel: pw GEMM (108 outs) + softmax + bilinear deform conv.
__global__ __launch_bounds__(256) void k_mega(const float* __restrict__ t_off,
                                              const float* __restrict__ t_m,
                                              const float* __restrict__ xT,
                                              const float* __restrict__ wT,
                                              const float* __restrict__ wdefT,
                                              const float* __restrict__ ad,
                                              const float* __restrict__ bpo,
                                              const float* __restrict__ bpm,
                                              const float* __restrict__ bias,
                                              float* __restrict__ out) {
    int tid = threadIdx.x;
    int bid = blockIdx.x;
    int b = bid >> 6;
    int p = (bid & 63) * 256 + tid;
    int row = p >> 7, col = p & 127;

    float facc[72], macc[36];
#pragma unroll
    for (int o = 0; o < 72; ++o) facc[o] = bpo[o];
#pragma unroll
    for (int o = 0; o < 36; ++o) macc[o] = bpm[o];

    const float* adb = ad + b * 256;
    const float* to = t_off + (size_t)b * 64 * HW + p;
    const float* tm = t_m + (size_t)b * 64 * HW + p;
#pragma unroll 4
    for (int c = 0; c < 64; ++c) {
        float aof = adb[c * 4 + 0], dof = adb[c * 4 + 1];
        float amf = adb[c * 4 + 2], dmf = adb[c * 4 + 3];
        float no = fmaf(aof, to[c * HW], dof);
        float nm = fmaf(amf, tm[c * HW], dmf);
        const float* wr = wT + c * 108;
#pragma unroll
        for (int o = 0; o < 72; ++o) facc[o] = fmaf(wr[o], no, facc[o]);
#pragma unroll
        for (int o = 0; o < 36; ++o) macc[o] = fmaf(wr[72 + o], nm, macc[o]);
    }

    // softmax over k within each group
#pragma unroll
    for (int g = 0; g < 4; ++g) {
        float mx = macc[g * 9];
#pragma unroll
        for (int k = 1; k < 9; ++k) mx = fmaxf(mx, macc[g * 9 + k]);
        float s = 0.f;
#pragma unroll
        for (int k = 0; k < 9; ++k) {
            float e = __expf(macc[g * 9 + k] - mx);
            macc[g * 9 + k] = e;
            s += e;
        }
        float inv = 1.f / s;
#pragma unroll
        for (int k = 0; k < 9; ++k) macc[g * 9 + k] *= inv;
    }

    float* outp = out + (size_t)b * 64 * HW + p;
#pragma unroll
    for (int g = 0; g < 4; ++g) {
        float acc[16];
#pragma unroll
        for (int o = 0; o < 16; ++o) acc[o] = 0.f;
        const float* xg = xT + ((size_t)(b * 4 + g)) * HW * 16;
        const float* wg = wdefT + g * 2304;
#pragma unroll
        for (int k = 0; k < 9; ++k) {
            float py = (float)(row + k / 3 - 1) + facc[g * 18 + k * 2 + 0];
            float px = (float)(col + k % 3 - 1) + facc[g * 18 + k * 2 + 1];
            float y0f = floorf(py), x0f = floorf(px);
            float wy = py - y0f, wx = px - x0f;
            int iy0 = (int)y0f, ix0 = (int)x0f;
            int iy1 = iy0 + 1, ix1 = ix0 + 1;
            float fy0 = (iy0 >= 0 && iy0 < IMG_H) ? (1.f - wy) : 0.f;
            float fy1 = (iy1 >= 0 && iy1 < IMG_H) ? wy : 0.f;
            float fx0 = (ix0 >= 0 && ix0 < IMG_W) ? (1.f - wx) : 0.f;
            float fx1 = (ix1 >= 0 && ix1 < IMG_W) ? wx : 0.f;
            float mk = macc[g * 9 + k];
            float f00 = fy0 * fx0 * mk, f01 = fy0 * fx1 * mk;
            float f10 = fy1 * fx0 * mk, f11 = fy1 * fx1 * mk;
            int yc0 = iy0 < 0 ? 0 : (iy0 > 127 ? 127 : iy0);
            int yc1 = iy1 < 0 ? 0 : (iy1 > 127 ? 127 : iy1);
            int xc0 = ix0 < 0 ? 0 : (ix0 > 127 ? 127 : ix0);
            int xc1 = ix1 < 0 ? 0 : (ix1 > 127 ? 127 : ix1);
            const float* r00 = xg + (size_t)(yc0 * IMG_W + xc0) * 16;
            const float* r01 = xg + (size_t)(yc0 * IMG_W + xc1) * 16;
            const float* r10 = xg + (size_t)(yc1 * IMG_W + xc0) * 16;
            const float* r11 = xg + (size_t)(yc1 * IMG_W + xc1) * 16;
            const float* wk = wg + k * 256;
#pragma unroll 4
            for (int c = 0; c < 16; ++c) {
                float v = f00 * r00[c] + f01 * r01[c] + f10 * r10[c] + f11 * r11[c];
#pragma unroll
                for (int o = 0; o < 16; ++o)
                    acc[o] = fmaf(wk[c * 16 + o], v, acc[o]);
            }
        }
#pragma unroll
        for (int o = 0; o < 16; ++o)
            outp[(size_t)(g * 16 + o) * HW] = acc[o] + bias[g * 16 + o];
    }
}

// ---------------------------------------------------------------------------
extern "C" void kernel_launch(void* const* d_in, const int* in_sizes, int n_in,
                              void* d_out, int out_size, void* d_ws, size_t ws_size,
                              hipStream_t stream) {
    const float* x        = (const float*)d_in[0];
    const float* w_dw_off = (const float*)d_in[1];
    const float* b_dw_off = (const float*)d_in[2];
    const float* gn_off_g = (const float*)d_in[3];
    const float* gn_off_b = (const float*)d_in[4];
    const float* w_pw_off = (const float*)d_in[5];
    const float* b_pw_off = (const float*)d_in[6];
    const float* w_dw_m   = (const float*)d_in[7];
    const float* b_dw_m   = (const float*)d_in[8];
    const float* gn_m_g   = (const float*)d_in[9];
    const float* gn_m_b   = (const float*)d_in[10];
    const float* w_pw_m   = (const float*)d_in[11];
    const float* b_pw_m   = (const float*)d_in[12];
    const float* weight   = (const float*)d_in[13];
    const float* bias     = (const float*)d_in[14];

    float* ws = (float*)d_ws;
    float* t_off = ws + OFF_TOFF;
    float* t_m   = ws + OFF_TM;
    float* xT    = ws + OFF_XT;
    float* wT    = ws + OFF_WT;
    float* wdefT = ws + OFF_WDEF;
    float* part  = ws + OFF_PART;
    float* adb   = ws + OFF_AD;

    k_prep<<<63, 256, 0, stream>>>(w_pw_off, w_pw_m, weight, ws);
    k_trans<<<2048, 256, 0, stream>>>(x, xT);
    k_dw<<<8192, 256, 0, stream>>>(x, w_dw_off, b_dw_off, w_dw_m, b_dw_m,
                                   t_off, t_m, part);
    k_fin<<<8, 256, 0, stream>>>(part, gn_off_g, gn_off_b, gn_m_g, gn_m_b, adb);
    k_mega<<<512, 256, 0, stream>>>(t_off, t_m, xT, wT, wdefT, adb,
                                    b_pw_off, b_pw_m, bias, (float*)d_out);
}